// Round 1
// 85.245 us; speedup vs baseline: 1.0169x; 1.0169x over previous
//
#include <hip/hip_runtime.h>

#define BB 2
#define NN 512
#define FF 128
#define HH 256
#define TI 4     // i-rows per K2 block

typedef float v2f __attribute__((ext_vector_type(2)));
typedef _Float16 v2h __attribute__((ext_vector_type(2)));
typedef unsigned int u32;
typedef unsigned long long u64;
__device__ __forceinline__ v2f splat2(float s) { return (v2f){s, s}; }

#if defined(__has_builtin)
#if __has_builtin(__builtin_amdgcn_fdot2)
#define HAVE_DOT2 1
#endif
#endif

__device__ __forceinline__ u32 pack16(float a, float b) {
  v2h p; p.x = (_Float16)a; p.y = (_Float16)b;
  return __builtin_bit_cast(u32, p);
}
__device__ __forceinline__ v2h as_v2h(u32 u) { return __builtin_bit_cast(v2h, u); }

// one e-row step over an h-quad: acc += w . relu(s + q), 4 h at a time
__device__ __forceinline__ float erow(u64 sv, v2h qa, v2h qb, v2h wa, v2h wb, float acc) {
  uint2 s_ = __builtin_bit_cast(uint2, sv);
  v2h sa = as_v2h(s_.x), sb = as_v2h(s_.y);
#ifdef HAVE_DOT2
  const v2h z2 = {(_Float16)0.f, (_Float16)0.f};
  acc = __builtin_amdgcn_fdot2(__builtin_elementwise_max(sa + qa, z2), wa, acc, false);
  acc = __builtin_amdgcn_fdot2(__builtin_elementwise_max(sb + qb, z2), wb, acc, false);
#else
  acc = fmaf(fmaxf((float)sa.x + (float)qa.x, 0.f), (float)wa.x, acc);
  acc = fmaf(fmaxf((float)sa.y + (float)qa.y, 0.f), (float)wa.y, acc);
  acc = fmaf(fmaxf((float)sb.x + (float)qb.x, 0.f), (float)wb.x, acc);
  acc = fmaf(fmaxf((float)sb.y + (float)qb.y, 0.f), (float)wb.y, acc);
#endif
  return acc;
}

// ---------------- K1: s16 / q-quads = f16-packed x . w1 halves ----------------
// Grid (64, 8). h0 = by*64. by<4 -> s-half (s16[bn][h] f16, +b1 folded);
// by>=4 -> q-half (q16q[hq][bn] u64 = packed h-quad). w216 written by one block.
__global__ __launch_bounds__(256) void k1_pq(const float* __restrict__ x,
    const float* __restrict__ w1, const float* __restrict__ b1,
    const float* __restrict__ w2,
    u32* __restrict__ s16, u64* __restrict__ q16q, u32* __restrict__ w216) {
  __shared__ __align__(16) float w1_l[64][FF];   // 32 KB, rotated
  __shared__ float tmp[64][17];                  // transpose buffer (q-half)
  const int t   = threadIdx.x;
  const int bn0 = blockIdx.x * 16;
  const int h0  = blockIdx.y * 64;               // h' base
  const bool qh = (h0 >= HH);
  const int rowbase = qh ? (h0 - HH) : h0;
  const int colbase = qh ? FF : 0;

  #pragma unroll
  for (int k = 0; k < 8; ++k) {
    int idx = t + 256 * k;
    int r = idx >> 5, c4 = (idx & 31) * 4;
    float4 v = *(const float4*)(w1 + (rowbase + r) * (2 * FF) + colbase + c4);
    *(float4*)&w1_l[r][(c4 + 4 * r) & 127] = v;
  }
  __syncthreads();

  const int l  = t & 63;
  const int sb = __builtin_amdgcn_readfirstlane(t >> 6);
  const float* xr = x + (bn0 + sb * 4) * FF;
  float acc0 = 0.f, acc1 = 0.f, acc2 = 0.f, acc3 = 0.f;

  #pragma unroll 4
  for (int f4 = 0; f4 < FF; f4 += 4) {
    float4 wv = *(float4*)&w1_l[l][(f4 + 4 * l) & 127];
    float4 x0 = *(const float4*)(xr + f4);
    float4 x1 = *(const float4*)(xr + FF + f4);
    float4 x2 = *(const float4*)(xr + 2 * FF + f4);
    float4 x3 = *(const float4*)(xr + 3 * FF + f4);
    acc0 = fmaf(x0.x, wv.x, acc0); acc0 = fmaf(x0.y, wv.y, acc0);
    acc0 = fmaf(x0.z, wv.z, acc0); acc0 = fmaf(x0.w, wv.w, acc0);
    acc1 = fmaf(x1.x, wv.x, acc1); acc1 = fmaf(x1.y, wv.y, acc1);
    acc1 = fmaf(x1.z, wv.z, acc1); acc1 = fmaf(x1.w, wv.w, acc1);
    acc2 = fmaf(x2.x, wv.x, acc2); acc2 = fmaf(x2.y, wv.y, acc2);
    acc2 = fmaf(x2.z, wv.z, acc2); acc2 = fmaf(x2.w, wv.w, acc2);
    acc3 = fmaf(x3.x, wv.x, acc3); acc3 = fmaf(x3.y, wv.y, acc3);
    acc3 = fmaf(x3.z, wv.z, acc3); acc3 = fmaf(x3.w, wv.w, acc3);
  }

  const int bn = bn0 + sb * 4;
  if (!qh) {
    float bv = b1[h0 + l];
    ushort* sp = (ushort*)s16;                   // s16 as [bn][h] f16
    sp[(bn    ) * HH + h0 + l] = __builtin_bit_cast(ushort, (_Float16)(acc0 + bv));
    sp[(bn + 1) * HH + h0 + l] = __builtin_bit_cast(ushort, (_Float16)(acc1 + bv));
    sp[(bn + 2) * HH + h0 + l] = __builtin_bit_cast(ushort, (_Float16)(acc2 + bv));
    sp[(bn + 3) * HH + h0 + l] = __builtin_bit_cast(ushort, (_Float16)(acc3 + bv));
  } else {
    tmp[l][sb * 4]     = acc0;
    tmp[l][sb * 4 + 1] = acc1;
    tmp[l][sb * 4 + 2] = acc2;
    tmp[l][sb * 4 + 3] = acc3;
    __syncthreads();
    {                                            // 16 hq x 16 bn u64 quads
      int rq = t >> 4, c = t & 15;
      u32 lo = pack16(tmp[4 * rq][c],     tmp[4 * rq + 1][c]);
      u32 hi = pack16(tmp[4 * rq + 2][c], tmp[4 * rq + 3][c]);
      q16q[(u64)(((h0 - HH) >> 2) + rq) * (BB * NN) + bn0 + c] =
          (u64)lo | ((u64)hi << 32);
    }
    if (blockIdx.x == 0 && h0 == HH && t < HH / 2)
      w216[t] = pack16(w2[2 * t], w2[2 * t + 1]);
  }
}

// ---------------- K2: e -> leaky -> mask -> softmax -> next_h ----------------
// Block = (b, 4 i-rows), 1024 threads = 16 waves.
// e-phase: wave = (h-half hg, 64-j slice sl); h-quad u64 loads, fp32 acc.
__global__ __launch_bounds__(1024) void k2_attn(const u32* __restrict__ s16,
    const u64* __restrict__ q16q, const u32* __restrict__ w216,
    const float* __restrict__ x, const float* __restrict__ b2,
    const int* __restrict__ adj, float* __restrict__ out) {
  __shared__ __align__(16) float pe[2][TI][NN];        // 16 KB (h-half partials)
  __shared__ __align__(16) float e_l[TI][NN];          // 8 KB
  __shared__ __align__(16) float part_l[16][TI][FF];   // 32 KB
  __shared__ float red_m[TI][4];
  __shared__ float red_s[TI][4];

  const int blk  = blockIdx.x;
  const int b    = blk >> 7;                // / 128
  const int i0   = (blk & 127) * TI;
  const int t    = threadIdx.x;             // 0..1023
  const int wvid = __builtin_amdgcn_readfirstlane(t >> 6);
  const int ln   = t & 63;

  // ---- e-phase ----
  {
    const int hg = wvid >> 3;               // h-quad range [hg*32, +32)
    const int sl = wvid & 7;                // j slice, lane j = sl*64+ln
    const int j  = sl * 64 + ln;
    const u64* qp = q16q + (u64)(hg * 32) * (BB * NN) + b * NN + j;
    const u64* sp = (const u64*)s16 + (u64)(b * NN + i0) * (HH / 4) + hg * 32;  // uniform -> s_load
    const u64* wp = (const u64*)w216 + hg * 32;                                 // uniform -> s_load
    float a0 = 0.f, a1 = 0.f, a2 = 0.f, a3 = 0.f;
    #pragma unroll 8
    for (int hq = 0; hq < 32; ++hq) {
      u64 q8 = qp[(u64)hq * (BB * NN)];     // coalesced 8B/lane
      uint2 qv = __builtin_bit_cast(uint2, q8);
      v2h qa = as_v2h(qv.x), qb = as_v2h(qv.y);
      uint2 wu = __builtin_bit_cast(uint2, wp[hq]);
      v2h wa = as_v2h(wu.x), wb = as_v2h(wu.y);
      a0 = erow(sp[hq],                 qa, qb, wa, wb, a0);
      a1 = erow(sp[(HH / 4) + hq],      qa, qb, wa, wb, a1);
      a2 = erow(sp[2 * (HH / 4) + hq],  qa, qb, wa, wb, a2);
      a3 = erow(sp[3 * (HH / 4) + hq],  qa, qb, wa, wb, a3);
    }
    pe[hg][0][j] = a0; pe[hg][1][j] = a1;
    pe[hg][2][j] = a2; pe[hg][3][j] = a3;
  }
  __syncthreads();

  // ---- fused combine (bias+leaky+mask) + softmax ----
  // wave = (ti = wvid>>2, j-quarter = wvid&3), 2 vals/lane
  {
    const int ti = wvid >> 2, qtr = wvid & 3;
    const int j2 = qtr * 128 + 2 * ln;
    const float b2v = b2[0];
    float2 p0 = *(float2*)&pe[0][ti][j2];
    float2 p1 = *(float2*)&pe[1][ti][j2];
    int2 av = *(const int2*)&adj[(b * NN + i0 + ti) * NN + j2];   // coalesced 8B
    float vx = p0.x + p1.x + b2v; vx = vx > 0.f ? vx : 0.04f * vx;
    float vy = p0.y + p1.y + b2v; vy = vy > 0.f ? vy : 0.04f * vy;
    vx = (av.x > 0) ? vx : -9.0e15f;
    vy = (av.y > 0) ? vy : -9.0e15f;

    float m = fmaxf(vx, vy);
    #pragma unroll
    for (int off = 32; off > 0; off >>= 1) m = fmaxf(m, __shfl_xor(m, off, 64));
    if (ln == 0) red_m[ti][qtr] = m;
    __syncthreads();
    m = fmaxf(fmaxf(red_m[ti][0], red_m[ti][1]), fmaxf(red_m[ti][2], red_m[ti][3]));
    vx = __expf(vx - m); vy = __expf(vy - m);
    float zs = vx + vy;
    #pragma unroll
    for (int off = 32; off > 0; off >>= 1) zs += __shfl_xor(zs, off, 64);
    if (ln == 0) red_s[ti][qtr] = zs;
    __syncthreads();
    float inv = 1.f / ((red_s[ti][0] + red_s[ti][1]) + (red_s[ti][2] + red_s[ti][3]));
    vx *= inv; vy *= inv;
    *(float2*)&e_l[ti][j2] = (float2){vx, vy};
    if (blk == 0 && ti == 0) {                // attention[0,0,:] extra output
      out[BB * NN * FF + j2]     = vx;
      out[BB * NN * FF + j2 + 1] = vy;
    }
  }
  __syncthreads();

  // ---- next_h: wave owns 32 j-rows (x read once per block); lane = f-pair ----
  {
    const int jb = wvid * 32;
    const int f2 = 2 * ln;
    v2f acc[TI];
    #pragma unroll
    for (int ti = 0; ti < TI; ++ti) acc[ti] = (v2f){0.f, 0.f};

    #pragma unroll 2
    for (int g = 0; g < 8; ++g) {
      const int j0 = jb + g * 4;
      float4 aa[TI];
      #pragma unroll
      for (int ti = 0; ti < TI; ++ti) aa[ti] = *(float4*)&e_l[ti][j0];  // broadcast b128
      #pragma unroll
      for (int k = 0; k < 4; ++k) {
        v2f x2 = *(const v2f*)(x + (b * NN + j0 + k) * FF + f2);        // coalesced 512B
        #pragma unroll
        for (int ti = 0; ti < TI; ++ti) {
          float w = (k == 0) ? aa[ti].x : (k == 1) ? aa[ti].y : (k == 2) ? aa[ti].z : aa[ti].w;
          acc[ti] = __builtin_elementwise_fma(splat2(w), x2, acc[ti]);
        }
      }
    }
    #pragma unroll
    for (int ti = 0; ti < TI; ++ti) *(v2f*)&part_l[wvid][ti][f2] = acc[ti];
  }
  __syncthreads();
  if (t < TI * FF) {                         // 512 cells
    const int ti = t >> 7, f = t & 127;
    float r = 0.f;
    #pragma unroll
    for (int w = 0; w < 16; ++w) r += part_l[w][ti][f];
    out[(b * NN + i0 + ti) * FF + f] = r;
  }
}

extern "C" void kernel_launch(void* const* d_in, const int* in_sizes, int n_in,
                              void* d_out, int out_size, void* d_ws, size_t ws_size,
                              hipStream_t stream) {
  const float* x   = (const float*)d_in[0];
  const float* w1  = (const float*)d_in[1];
  const float* b1  = (const float*)d_in[2];
  const float* w2  = (const float*)d_in[3];
  const float* b2  = (const float*)d_in[4];
  const int*   adj = (const int*)  d_in[5];
  float* out = (float*)d_out;

  u32* s16  = (u32*)d_ws;                   // [1024][128] u32 (f16 h-pairs) = 512 KB
  u64* q16q = (u64*)(s16 + BB * NN * (HH / 2));  // [64 hq][1024 bn] u64 = 512 KB
  u32* w216 = (u32*)(q16q + 64 * (BB * NN));     // [128] u32

  dim3 g1(BB * NN / 16, (2 * HH) / 64);     // (64, 8) = 512 blocks
  k1_pq  <<<g1, 256, 0, stream>>>(x, w1, b1, w2, s16, q16q, w216);
  k2_attn<<<BB * NN / TI, 1024, 0, stream>>>(s16, q16q, w216, x, b2, adj, out);
}